// Round 8
// baseline (438.823 us; speedup 1.0000x reference)
//
#include <hip/hip_runtime.h>
#include <math.h>

// Problem dims
#define BB 2048
#define CC 64
#define BERT 768
#define N_CTRY 250
#define N_CODES 654

// ws float offsets
#define OFF_PCHAT   0                          // [250][24] normalized country projections
#define OFF_CODEHAT (N_CTRY * 24)              // [654][8]  normalized code embeddings

// ---------------------------------------------------------------------------
// Kernel 1 (tiny): normalized country projections + normalized code rows.
// blocks 0..249: one block per country row. blocks 250..252: code rows.
// ---------------------------------------------------------------------------
__global__ __launch_bounds__(256) void k1_precompute(
    const float* __restrict__ ctab, const float* __restrict__ W_cet,
    const float* __restrict__ b_cet, const float* __restrict__ code_emb,
    float* __restrict__ ws) {
  float* pchat   = ws + OFF_PCHAT;
  float* codehat = ws + OFF_CODEHAT;
  const int bid = blockIdx.x;
  const int tid = threadIdx.x;
  const int w = tid >> 6, lane = tid & 63;
  if (bid < N_CTRY) {
    __shared__ float s_p24[24];
    __shared__ float s_inv1;
    const float4* in4 = (const float4*)(ctab + (size_t)bid * BERT);
    float4 xa[3];
#pragma unroll
    for (int i = 0; i < 3; ++i) xa[i] = in4[lane + 64 * i];
    float acc6[6];
#pragma unroll
    for (int jj = 0; jj < 6; ++jj) acc6[jj] = 0.f;
#pragma unroll
    for (int jj = 0; jj < 6; ++jj) {
      const int j = w * 6 + jj;
      const float4* wr = (const float4*)(W_cet + (size_t)j * BERT);
#pragma unroll
      for (int i = 0; i < 3; ++i) {
        float4 wv = wr[lane + 64 * i];
        acc6[jj] += xa[i].x * wv.x + xa[i].y * wv.y + xa[i].z * wv.z + xa[i].w * wv.w;
      }
    }
#pragma unroll
    for (int s = 32; s >= 1; s >>= 1)
#pragma unroll
      for (int jj = 0; jj < 6; ++jj) acc6[jj] += __shfl_xor(acc6[jj], s, 64);
    if (lane == 0) {
#pragma unroll
      for (int jj = 0; jj < 6; ++jj) s_p24[w * 6 + jj] = acc6[jj] + b_cet[w * 6 + jj];
    }
    __syncthreads();
    if (tid == 0) {
      float ss = 0.f;
      for (int k = 0; k < 24; ++k) ss += s_p24[k] * s_p24[k];
      s_inv1 = 1.f / fmaxf(sqrtf(ss), 1e-8f);
    }
    __syncthreads();
    if (tid < 24) pchat[bid * 24 + tid] = s_p24[tid] * s_inv1;
  } else {
    const int idx = (bid - N_CTRY) * 256 + tid;
    if (idx < N_CODES) {
      float v[8];
      float ss = 0.f;
#pragma unroll
      for (int k = 0; k < 8; ++k) { v[k] = code_emb[idx * 8 + k]; ss += v[k] * v[k]; }
      const float inv = 1.f / fmaxf(sqrtf(ss), 1e-8f);
#pragma unroll
      for (int k = 0; k < 8; ++k) codehat[idx * 8 + k] = v[k] * inv;
    }
  }
}

// ---------------------------------------------------------------------------
// Kernel 2 (self-contained fusion, NO barrier): 512 blocks x 512 threads.
// Block handles 4 rows end-to-end.
//   Projection: 8 waves; wave w -> (row r = w>>1, j-half h = w&1).
//     lane = (kq = lane>>2, jsub = lane&3); owns j = 40h + 4g + jsub, g<10,
//     over a 48-elem interleaved k-strip. Per-lane state: acc[10] + x4[12]
//     (~60 regs; R4's spilling layout halved). Weights streamed from L2.
//     Butterfly over kq bits only; kq==0 lanes write s_proj (LDS).
//   Classify: waves 0-3 -> rows 0-3, lane = class; pchat from LDS s_pch,
//     codehat/gaz direct; softmax = one wave butterfly. Waves 4-7 idle.
// ---------------------------------------------------------------------------
__global__ __launch_bounds__(512) void k2_projclass(
    const float* __restrict__ place, const float* __restrict__ other,
    const float* __restrict__ doc,
    const float* __restrict__ W_t2c, const float* __restrict__ b_t2c,
    const float* __restrict__ W_code, const float* __restrict__ b_code,
    const float* __restrict__ W_ctx, const float* __restrict__ b_ctx,
    const int* __restrict__ fcodes, const int* __restrict__ ccodes,
    const float* __restrict__ gaz,
    const float* __restrict__ W_mix1, const float* __restrict__ b_mix1,
    const float* __restrict__ W_mix2, const float* __restrict__ b_mix2,
    const float* __restrict__ W_last, const float* __restrict__ b_last,
    const float* __restrict__ ws, float* __restrict__ out) {
  __shared__ float s_pch[N_CTRY * 25];   // 25 KB padded
  __shared__ float s_proj[4][80];
  __shared__ float s_inv[4][4];

  const int tid = threadIdx.x;
  const int w = tid >> 6, lane = tid & 63;
  const int kq = lane >> 2, jsub = lane & 3;
  const int row0 = blockIdx.x * 4;
  const int r = w >> 1, h = w & 1;           // wave -> (row, j-half)

  // ---- projection ----
  {
    const int row = row0 + r;
    // x strip for this lane (register-held; 4-lane redundancy shares cachelines)
    // Both halves need place (h=0: j<24&24..31; h=1: j 40..55 ctx(other), 56.. doc)
    // Per-g tensor selection below reloads x when the tensor changes.
    float acc[10];
    const float* xcur = nullptr;
    float4 x4[12];
#pragma unroll
    for (int g = 0; g < 10; ++g) {
      const int j0 = 40 * h + 4 * g;         // wave-uniform
      const float* wbase; const float* xbase; int jb;
      if (j0 < 24)      { wbase = W_t2c;  jb = j0;      xbase = place; }
      else if (j0 < 32) { wbase = W_code; jb = j0 - 24; xbase = place; }
      else if (j0 < 56) { wbase = W_ctx;  jb = j0 - 32; xbase = other; }
      else              { wbase = W_ctx;  jb = j0 - 56; xbase = doc;   }
      if (xbase != xcur) {
        const float4* xr = (const float4*)(xbase + (size_t)row * BERT);
#pragma unroll
        for (int i = 0; i < 12; ++i) x4[i] = xr[kq + 16 * i];
        xcur = xbase;
      }
      const float4* wr = (const float4*)(wbase + (size_t)(jb + jsub) * BERT);
      float s0 = 0.f, s1 = 0.f, s2 = 0.f, s3 = 0.f;
#pragma unroll
      for (int i = 0; i < 12; i += 4) {
        float4 w0 = wr[kq + 16 * (i + 0)];
        float4 w1 = wr[kq + 16 * (i + 1)];
        float4 w2 = wr[kq + 16 * (i + 2)];
        float4 w3 = wr[kq + 16 * (i + 3)];
        s0 += x4[i+0].x*w0.x + x4[i+0].y*w0.y + x4[i+0].z*w0.z + x4[i+0].w*w0.w;
        s1 += x4[i+1].x*w1.x + x4[i+1].y*w1.y + x4[i+1].z*w1.z + x4[i+1].w*w1.w;
        s2 += x4[i+2].x*w2.x + x4[i+2].y*w2.y + x4[i+2].z*w2.z + x4[i+2].w*w2.w;
        s3 += x4[i+3].x*w3.x + x4[i+3].y*w3.y + x4[i+3].z*w3.z + x4[i+3].w*w3.w;
      }
      acc[g] = (s0 + s1) + (s2 + s3);
    }
    // batched butterfly over kq bits (10 independent chains)
#pragma unroll
    for (int m = 4; m <= 32; m <<= 1)
#pragma unroll
      for (int g = 0; g < 10; ++g) acc[g] += __shfl_xor(acc[g], m, 64);
    if (kq == 0) {
#pragma unroll
      for (int g = 0; g < 10; ++g) {
        const int j = 40 * h + 4 * g + jsub;
        const float bias = (j < 24) ? b_t2c[j] : (j < 32) ? b_code[j - 24]
                         : (j < 56) ? b_ctx[j - 32] : b_ctx[j - 56];
        s_proj[r][j] = acc[g] + bias;
      }
    }
  }

  // ---- stage pchat into LDS (padded stride 25) while proj writes settle ----
  {
    const float* pch = ws + OFF_PCHAT;
    for (int e = tid; e < N_CTRY * 24; e += 512)
      s_pch[(e / 24) * 25 + (e % 24)] = pch[e];
  }
  __syncthreads();

  // ---- group inverse norms ----
  if (tid < 16) {
    const int rr = tid >> 2, g = tid & 3;
    const int st[5] = {0, 24, 32, 56, 80};
    float ss = 0.f;
    for (int k = st[g]; k < st[g + 1]; ++k) ss += s_proj[rr][k] * s_proj[rr][k];
    s_inv[rr][g] = 1.f / fmaxf(sqrtf(ss), 1e-8f);
  }
  __syncthreads();

  // ---- classify: waves 0-3 -> rows 0-3 ----
  if (w < 4) {
    const int row = row0 + w;
    const int cidx = ccodes[row * CC + lane];
    const int fidx = fcodes[row * CC + lane];

    float cc[24];
#pragma unroll
    for (int k = 0; k < 24; ++k) cc[k] = s_pch[cidx * 25 + k];
    float cd[8];
    {
      const float4* q4 = (const float4*)(ws + OFF_CODEHAT + fidx * 8);
#pragma unroll
      for (int i = 0; i < 2; ++i) {
        float4 v = q4[i];
        cd[4*i+0] = v.x; cd[4*i+1] = v.y; cd[4*i+2] = v.z; cd[4*i+3] = v.w;
      }
    }

    float sc = 0.f, so = 0.f, sd = 0.f, sq = 0.f;
#pragma unroll
    for (int k = 0; k < 24; ++k) {
      const float ck = cc[k];
      sc += s_proj[w][k] * ck;
      so += s_proj[w][32 + k] * ck;
      sd += s_proj[w][56 + k] * ck;
    }
#pragma unroll
    for (int k = 0; k < 8; ++k) sq += s_proj[w][24 + k] * cd[k];

    float f[13];
    f[0] = sc * s_inv[w][0];
    f[1] = sq * s_inv[w][1];
    f[2] = so * s_inv[w][2];
    f[3] = sd * s_inv[w][3];
    {
      const float* g = gaz + (size_t)(row * CC + lane) * 9;
      float4 ga = ((const float4*)g)[0];
      float4 gb = ((const float4*)g)[1];
      f[4] = ga.x; f[5] = ga.y; f[6] = ga.z; f[7] = ga.w;
      f[8] = gb.x; f[9] = gb.y; f[10] = gb.z; f[11] = gb.w;
      f[12] = g[8];
    }

    float h1[24];
#pragma unroll
    for (int j = 0; j < 24; ++j) {
      float a = b_mix1[j];
#pragma unroll
      for (int i = 0; i < 13; ++i) a += W_mix1[j * 13 + i] * f[i];
      h1[j] = 1.f / (1.f + __expf(-a));
    }
    float h2[24];
#pragma unroll
    for (int j = 0; j < 24; ++j) {
      float a = b_mix2[j];
#pragma unroll
      for (int i = 0; i < 24; ++i) a += W_mix2[j * 24 + i] * h1[i];
      h2[j] = 1.f / (1.f + __expf(-a));
    }
    float last = b_last[0];
#pragma unroll
    for (int k = 0; k < 24; ++k) last += W_last[k] * h2[k];

    float mx = last;
#pragma unroll
    for (int s = 32; s >= 1; s >>= 1) mx = fmaxf(mx, __shfl_xor(mx, s, 64));
    const float e = __expf(last - mx);
    float ssum = e;
#pragma unroll
    for (int s = 32; s >= 1; s >>= 1) ssum += __shfl_xor(ssum, s, 64);
    out[row * CC + lane] = e / ssum;
  }
}

// ---------------------------------------------------------------------------
extern "C" void kernel_launch(void* const* d_in, const int* in_sizes, int n_in,
                              void* d_out, int out_size, void* d_ws, size_t ws_size,
                              hipStream_t stream) {
  const float* place   = (const float*)d_in[0];
  const float* other   = (const float*)d_in[1];
  const float* doc     = (const float*)d_in[2];
  const int*   fcodes  = (const int*)d_in[3];
  const int*   ccodes  = (const int*)d_in[4];
  const float* gaz     = (const float*)d_in[5];
  const float* code_emb= (const float*)d_in[6];
  const float* ctab    = (const float*)d_in[7];
  const float* W_cet   = (const float*)d_in[8];
  const float* b_cet   = (const float*)d_in[9];
  const float* W_t2c   = (const float*)d_in[10];
  const float* b_t2c   = (const float*)d_in[11];
  const float* W_ctx   = (const float*)d_in[12];
  const float* b_ctx   = (const float*)d_in[13];
  const float* W_code  = (const float*)d_in[14];
  const float* b_code  = (const float*)d_in[15];
  const float* W_mix1  = (const float*)d_in[16];
  const float* b_mix1  = (const float*)d_in[17];
  const float* W_mix2  = (const float*)d_in[18];
  const float* b_mix2  = (const float*)d_in[19];
  const float* W_last  = (const float*)d_in[20];
  const float* b_last  = (const float*)d_in[21];
  float* ws  = (float*)d_ws;
  float* out = (float*)d_out;

  k1_precompute<<<N_CTRY + 3, 256, 0, stream>>>(ctab, W_cet, b_cet, code_emb, ws);
  k2_projclass<<<BB / 4, 512, 0, stream>>>(
      place, other, doc, W_t2c, b_t2c, W_code, b_code, W_ctx, b_ctx,
      fcodes, ccodes, gaz, W_mix1, b_mix1, W_mix2, b_mix2, W_last, b_last,
      ws, out);
}

// Round 9
// 146.148 us; speedup vs baseline: 3.0026x; 3.0026x over previous
//
#include <hip/hip_runtime.h>
#include <math.h>

// Problem dims
#define BB 2048
#define CC 64
#define BERT 768
#define N_CTRY 250
#define N_CODES 654

// ws layout (floats)
#define OFF_PCHAT   0                          // [250][24] normalized country projections
#define OFF_CODEHAT (250*24)                   // [654][8]  normalized code embeddings
#define OFF_XALL    (OFF_CODEHAT + 654*8)      // [2048][80] RAW projections (+bias)
#define OFF_SSQ     (OFF_XALL + 2048*80)       // [2048][10] per-(row,cb) sumsq partials

#define RPB 16                                 // rows streamed per projection block
#define ROWGRPS (BB / RPB)                     // 128
#define PROJ_BLOCKS (5 * ROWGRPS)              // 640 (5 column-blocks of 16 j's)

// ---------------------------------------------------------------------------
// Kernel 1 (fused grid): projection (weight-stationary, row-streaming,
// batched reduction) + country-table precompute + code-norm precompute.
//
//   blocks [0,640):   cb = bid/128 owns j in [16cb,16cb+16); wave w owns 4 j's;
//                     lane (kq=lane>>2, jsub=lane&3) owns j = 16cb+4w+jsub with
//                     a 48-elem k-strip. Weights (12 float4) loaded ONCE, then
//                     16 rows streamed (RPB 8->16 vs R6: halves weight refetch
//                     and loop overhead; acc[16]+wv[12] ~= 92 VGPR, no spill).
//                     Phase 1: independent per-row FMA chains -> acc[16].
//                     Phase 2: ONE batched 4-stage butterfly (16 indep chains).
//   blocks [640,890): country rows -> pchat (normalized)
//   blocks [890,893): code rows -> codehat (normalized)
// ---------------------------------------------------------------------------
__global__ __launch_bounds__(256) void k_proj(
    const float* __restrict__ place, const float* __restrict__ other,
    const float* __restrict__ doc,
    const float* __restrict__ W_t2c, const float* __restrict__ b_t2c,
    const float* __restrict__ W_code, const float* __restrict__ b_code,
    const float* __restrict__ W_ctx, const float* __restrict__ b_ctx,
    const float* __restrict__ ctab, const float* __restrict__ W_cet,
    const float* __restrict__ b_cet, const float* __restrict__ code_emb,
    float* __restrict__ ws) {
  __shared__ float s_ss[RPB][4];
  __shared__ float s_p24[24];
  __shared__ float s_inv1;

  const int bid = blockIdx.x;
  const int tid = threadIdx.x;
  const int w = tid >> 6, lane = tid & 63;

  if (bid < PROJ_BLOCKS) {
    float* xall = ws + OFF_XALL;
    float* ssq  = ws + OFF_SSQ;
    const int cb = bid / ROWGRPS;              // 0..4 (column block)
    const int rg = bid % ROWGRPS;
    const int row0 = rg * RPB;
    const int j0 = cb * 16 + w * 4;            // wave-uniform base j
    const float* wbase; const float* xbase; const float* bbase; int jb;
    if (j0 < 24)      { wbase = W_t2c;  bbase = b_t2c;  jb = j0;      xbase = place; }
    else if (j0 < 32) { wbase = W_code; bbase = b_code; jb = j0 - 24; xbase = place; }
    else if (j0 < 56) { wbase = W_ctx;  bbase = b_ctx;  jb = j0 - 32; xbase = other; }
    else              { wbase = W_ctx;  bbase = b_ctx;  jb = j0 - 56; xbase = doc;   }
    const int jsub = lane & 3, kq = lane >> 2;
    const float bias = bbase[jb + jsub];

    // stationary weights: this lane's j-row strip (12 float4 = 48 VGPR)
    float4 wv[12];
    {
      const float4* wr = (const float4*)(wbase + (size_t)(jb + jsub) * BERT);
#pragma unroll
      for (int i = 0; i < 12; ++i) wv[i] = wr[kq + 16 * i];
    }

    // phase 1: independent per-row dot-partials
    float acc[RPB];
#pragma unroll
    for (int r = 0; r < RPB; ++r) {
      const float4* xr = (const float4*)(xbase + (size_t)(row0 + r) * BERT);
      float s0 = 0.f, s1 = 0.f, s2 = 0.f, s3 = 0.f;
#pragma unroll
      for (int i = 0; i < 12; i += 4) {
        float4 a0 = xr[kq + 16 * (i + 0)];
        float4 a1 = xr[kq + 16 * (i + 1)];
        float4 a2 = xr[kq + 16 * (i + 2)];
        float4 a3 = xr[kq + 16 * (i + 3)];
        s0 += a0.x*wv[i+0].x + a0.y*wv[i+0].y + a0.z*wv[i+0].z + a0.w*wv[i+0].w;
        s1 += a1.x*wv[i+1].x + a1.y*wv[i+1].y + a1.z*wv[i+1].z + a1.w*wv[i+1].w;
        s2 += a2.x*wv[i+2].x + a2.y*wv[i+2].y + a2.z*wv[i+2].z + a2.w*wv[i+2].w;
        s3 += a3.x*wv[i+3].x + a3.y*wv[i+3].y + a3.z*wv[i+3].z + a3.w*wv[i+3].w;
      }
      acc[r] = (s0 + s1) + (s2 + s3);
    }

    // phase 2: ONE batched butterfly over kq bits (16 independent chains)
#pragma unroll
    for (int m = 4; m <= 32; m <<= 1)
#pragma unroll
      for (int r = 0; r < RPB; ++r) acc[r] += __shfl_xor(acc[r], m, 64);

    // bias, store, batched sumsq
    float v2[RPB];
#pragma unroll
    for (int r = 0; r < RPB; ++r) {
      const float val = acc[r] + bias;
      if (kq == 0) xall[(size_t)(row0 + r) * 80 + j0 + jsub] = val;
      v2[r] = val * val;
    }
#pragma unroll
    for (int r = 0; r < RPB; ++r) v2[r] += __shfl_xor(v2[r], 1, 64);
#pragma unroll
    for (int r = 0; r < RPB; ++r) v2[r] += __shfl_xor(v2[r], 2, 64);
    if (lane == 0) {
#pragma unroll
      for (int r = 0; r < RPB; ++r) s_ss[r][w] = v2[r];
    }
    __syncthreads();
    if (tid < RPB * 2) {
      const int r = tid >> 1, s = tid & 1;   // s=0: waves 0,1  s=1: waves 2,3
      ssq[(size_t)(row0 + r) * 10 + cb * 2 + s] = s_ss[r][2 * s] + s_ss[r][2 * s + 1];
    }
  } else if (bid < PROJ_BLOCKS + N_CTRY) {
    // ---------------- country-table projection path ----------------
    float* pchat = ws + OFF_PCHAT;
    const int b = bid - PROJ_BLOCKS;
    float4 xa[3];
#pragma unroll
    for (int i = 0; i < 3; ++i)
      xa[i] = ((const float4*)(ctab + (size_t)b * BERT))[lane + 64 * i];
    float acc6[6];
#pragma unroll
    for (int jj = 0; jj < 6; ++jj) acc6[jj] = 0.f;
#pragma unroll
    for (int jj = 0; jj < 6; ++jj) {
      const int j = w * 6 + jj;
      const float4* wr = (const float4*)(W_cet + (size_t)j * BERT);
#pragma unroll
      for (int i = 0; i < 3; ++i) {
        float4 wvv = wr[lane + 64 * i];
        acc6[jj] += xa[i].x * wvv.x + xa[i].y * wvv.y + xa[i].z * wvv.z + xa[i].w * wvv.w;
      }
    }
#pragma unroll
    for (int s = 32; s >= 1; s >>= 1)
#pragma unroll
      for (int jj = 0; jj < 6; ++jj) acc6[jj] += __shfl_xor(acc6[jj], s, 64);
    if (lane == 0) {
#pragma unroll
      for (int jj = 0; jj < 6; ++jj) s_p24[w * 6 + jj] = acc6[jj] + b_cet[w * 6 + jj];
    }
    __syncthreads();
    if (tid == 0) {
      float ss = 0.f;
      for (int k = 0; k < 24; ++k) ss += s_p24[k] * s_p24[k];
      s_inv1 = 1.f / fmaxf(sqrtf(ss), 1e-8f);
    }
    __syncthreads();
    if (tid < 24) pchat[b * 24 + tid] = s_p24[tid] * s_inv1;
  } else {
    // ---------------- code-embedding normalization path ----------------
    float* codehat = ws + OFF_CODEHAT;
    const int idx = (bid - PROJ_BLOCKS - N_CTRY) * 256 + tid;
    if (idx < N_CODES) {
      float v[8];
      float ss = 0.f;
#pragma unroll
      for (int k = 0; k < 8; ++k) { v[k] = code_emb[idx * 8 + k]; ss += v[k] * v[k]; }
      const float inv = 1.f / fmaxf(sqrtf(ss), 1e-8f);
#pragma unroll
      for (int k = 0; k < 8; ++k) codehat[idx * 8 + k] = v[k] * inv;
    }
  }
}

// ---------------------------------------------------------------------------
// Kernel 2: classify. 256 threads = 4 waves = 4 rows; lane = class.
// pchat staged in LDS (padded stride 25). codehat + gaz gathered directly
// (L1/L2-resident); xv/ssq wave-uniform scalar loads; softmax = one wave
// butterfly (C=64=wave).  [R6 verbatim — known-good, no spill]
// ---------------------------------------------------------------------------
__global__ __launch_bounds__(256) void k_classify(
    const int* __restrict__ fcodes, const int* __restrict__ ccodes,
    const float* __restrict__ gaz,
    const float* __restrict__ W_mix1, const float* __restrict__ b_mix1,
    const float* __restrict__ W_mix2, const float* __restrict__ b_mix2,
    const float* __restrict__ W_last, const float* __restrict__ b_last,
    const float* __restrict__ ws, float* __restrict__ out) {
  __shared__ float s_pch[N_CTRY * 25];     // 25 KB padded
  const int tid = threadIdx.x;
  const int w = tid >> 6, lane = tid & 63;
  const int row0 = blockIdx.x * 4;

  {
    const float* pch = ws + OFF_PCHAT;
    for (int e = tid; e < N_CTRY * 24; e += 256)
      s_pch[(e / 24) * 25 + (e % 24)] = pch[e];
  }
  __syncthreads();

  const int row = __builtin_amdgcn_readfirstlane(row0 + w);
  const float* xv = ws + OFF_XALL + (size_t)row * 80;   // uniform -> s_load
  const float* q  = ws + OFF_SSQ + (size_t)row * 10;    // uniform -> s_load
  const float g0 = q[0] + q[1] + q[2];
  const float g1 = q[3];
  const float g2 = q[4] + q[5] + q[6];
  const float g3 = q[7] + q[8] + q[9];
  const float inv0 = 1.f / fmaxf(sqrtf(g0), 1e-8f);
  const float inv1 = 1.f / fmaxf(sqrtf(g1), 1e-8f);
  const float inv2 = 1.f / fmaxf(sqrtf(g2), 1e-8f);
  const float inv3 = 1.f / fmaxf(sqrtf(g3), 1e-8f);

  const int cidx = ccodes[row * CC + lane];
  const int fidx = fcodes[row * CC + lane];

  float cc[24];
#pragma unroll
  for (int k = 0; k < 24; ++k) cc[k] = s_pch[cidx * 25 + k];
  float cd[8];
  {
    const float4* q4 = (const float4*)(ws + OFF_CODEHAT + fidx * 8);
#pragma unroll
    for (int i = 0; i < 2; ++i) {
      float4 v = q4[i];
      cd[4*i+0] = v.x; cd[4*i+1] = v.y; cd[4*i+2] = v.z; cd[4*i+3] = v.w;
    }
  }

  float sc = 0.f, so = 0.f, sd = 0.f, sq = 0.f;
#pragma unroll
  for (int k = 0; k < 24; ++k) {
    const float ck = cc[k];
    sc += xv[k] * ck;
    so += xv[32 + k] * ck;
    sd += xv[56 + k] * ck;
  }
#pragma unroll
  for (int k = 0; k < 8; ++k) sq += xv[24 + k] * cd[k];

  float f[13];
  f[0] = sc * inv0;
  f[1] = sq * inv1;
  f[2] = so * inv2;
  f[3] = sd * inv3;
  {
    const float* g = gaz + (size_t)(row * CC + lane) * 9;
    float4 ga = ((const float4*)g)[0];
    float4 gb = ((const float4*)g)[1];
    f[4] = ga.x; f[5] = ga.y; f[6] = ga.z; f[7] = ga.w;
    f[8] = gb.x; f[9] = gb.y; f[10] = gb.z; f[11] = gb.w;
    f[12] = g[8];
  }

  float h1[24];
#pragma unroll
  for (int j = 0; j < 24; ++j) {
    float a = b_mix1[j];
#pragma unroll
    for (int i = 0; i < 13; ++i) a += W_mix1[j * 13 + i] * f[i];
    h1[j] = 1.f / (1.f + __expf(-a));
  }
  float h2[24];
#pragma unroll
  for (int j = 0; j < 24; ++j) {
    float a = b_mix2[j];
#pragma unroll
    for (int i = 0; i < 24; ++i) a += W_mix2[j * 24 + i] * h1[i];
    h2[j] = 1.f / (1.f + __expf(-a));
  }
  float last = b_last[0];
#pragma unroll
  for (int k = 0; k < 24; ++k) last += W_last[k] * h2[k];

  float mx = last;
#pragma unroll
  for (int s = 32; s >= 1; s >>= 1) mx = fmaxf(mx, __shfl_xor(mx, s, 64));
  const float e = __expf(last - mx);
  float ssum = e;
#pragma unroll
  for (int s = 32; s >= 1; s >>= 1) ssum += __shfl_xor(ssum, s, 64);
  out[row * CC + lane] = e / ssum;
}

// ---------------------------------------------------------------------------
extern "C" void kernel_launch(void* const* d_in, const int* in_sizes, int n_in,
                              void* d_out, int out_size, void* d_ws, size_t ws_size,
                              hipStream_t stream) {
  const float* place   = (const float*)d_in[0];
  const float* other   = (const float*)d_in[1];
  const float* doc     = (const float*)d_in[2];
  const int*   fcodes  = (const int*)d_in[3];
  const int*   ccodes  = (const int*)d_in[4];
  const float* gaz     = (const float*)d_in[5];
  const float* code_emb= (const float*)d_in[6];
  const float* ctab    = (const float*)d_in[7];
  const float* W_cet   = (const float*)d_in[8];
  const float* b_cet   = (const float*)d_in[9];
  const float* W_t2c   = (const float*)d_in[10];
  const float* b_t2c   = (const float*)d_in[11];
  const float* W_ctx   = (const float*)d_in[12];
  const float* b_ctx   = (const float*)d_in[13];
  const float* W_code  = (const float*)d_in[14];
  const float* b_code  = (const float*)d_in[15];
  const float* W_mix1  = (const float*)d_in[16];
  const float* b_mix1  = (const float*)d_in[17];
  const float* W_mix2  = (const float*)d_in[18];
  const float* b_mix2  = (const float*)d_in[19];
  const float* W_last  = (const float*)d_in[20];
  const float* b_last  = (const float*)d_in[21];
  float* ws  = (float*)d_ws;
  float* out = (float*)d_out;

  // proj (640) + country (250) + code-norm (3) in one grid
  k_proj<<<PROJ_BLOCKS + N_CTRY + 3, 256, 0, stream>>>(
      place, other, doc, W_t2c, b_t2c, W_code, b_code, W_ctx, b_ctx,
      ctab, W_cet, b_cet, code_emb, ws);
  // classify: 4 rows/block
  k_classify<<<BB / 4, 256, 0, stream>>>(fcodes, ccodes, gaz, W_mix1, b_mix1,
                                         W_mix2, b_mix2, W_last, b_last, ws, out);
}

// Round 10
// 143.092 us; speedup vs baseline: 3.0667x; 1.0214x over previous
//
#include <hip/hip_runtime.h>
#include <math.h>

// Problem dims
#define BB 2048
#define CC 64
#define BERT 768
#define N_CTRY 250
#define N_CODES 654

// ws layout (floats)
#define OFF_PCHAT   0                          // [250][24] normalized country projections
#define OFF_CODEHAT (250*24)                   // [654][8]  normalized code embeddings
#define OFF_XALL    (OFF_CODEHAT + 654*8)      // [2048][80] RAW projections (+bias)
#define OFF_SSQ     (OFF_XALL + 2048*80)       // [2048][10] per-(row,cb) sumsq partials

#define RPB 8                                  // rows streamed per projection block (R6 best)
#define ROWGRPS (BB / RPB)                     // 256
#define PROJ_BLOCKS (5 * ROWGRPS)              // 1280 (5 column-blocks of 16 j's)

// ---------------------------------------------------------------------------
// Kernel 1 (fused grid): projection (weight-stationary, row-streaming,
// batched reduction) + country-table precompute + code-norm precompute.
// [R6-proven structure: ~92 VGPR, no spill, 1533 blocks]
// ---------------------------------------------------------------------------
__global__ __launch_bounds__(256) void k_proj(
    const float* __restrict__ place, const float* __restrict__ other,
    const float* __restrict__ doc,
    const float* __restrict__ W_t2c, const float* __restrict__ b_t2c,
    const float* __restrict__ W_code, const float* __restrict__ b_code,
    const float* __restrict__ W_ctx, const float* __restrict__ b_ctx,
    const float* __restrict__ ctab, const float* __restrict__ W_cet,
    const float* __restrict__ b_cet, const float* __restrict__ code_emb,
    float* __restrict__ ws) {
  __shared__ float s_ss[RPB][4];
  __shared__ float s_p24[24];
  __shared__ float s_inv1;

  const int bid = blockIdx.x;
  const int tid = threadIdx.x;
  const int w = tid >> 6, lane = tid & 63;

  if (bid < PROJ_BLOCKS) {
    float* xall = ws + OFF_XALL;
    float* ssq  = ws + OFF_SSQ;
    const int cb = bid / ROWGRPS;              // 0..4 (column block)
    const int rg = bid % ROWGRPS;
    const int row0 = rg * RPB;
    const int j0 = cb * 16 + w * 4;            // wave-uniform base j
    const float* wbase; const float* xbase; const float* bbase; int jb;
    if (j0 < 24)      { wbase = W_t2c;  bbase = b_t2c;  jb = j0;      xbase = place; }
    else if (j0 < 32) { wbase = W_code; bbase = b_code; jb = j0 - 24; xbase = place; }
    else if (j0 < 56) { wbase = W_ctx;  bbase = b_ctx;  jb = j0 - 32; xbase = other; }
    else              { wbase = W_ctx;  bbase = b_ctx;  jb = j0 - 56; xbase = doc;   }
    const int jsub = lane & 3, kq = lane >> 2;
    const float bias = bbase[jb + jsub];

    // stationary weights: this lane's j-row strip (12 float4 = 48 VGPR)
    float4 wv[12];
    {
      const float4* wr = (const float4*)(wbase + (size_t)(jb + jsub) * BERT);
#pragma unroll
      for (int i = 0; i < 12; ++i) wv[i] = wr[kq + 16 * i];
    }

    // phase 1: independent per-row dot-partials
    float acc[RPB];
#pragma unroll
    for (int r = 0; r < RPB; ++r) {
      const float4* xr = (const float4*)(xbase + (size_t)(row0 + r) * BERT);
      float s0 = 0.f, s1 = 0.f, s2 = 0.f, s3 = 0.f;
#pragma unroll
      for (int i = 0; i < 12; i += 4) {
        float4 a0 = xr[kq + 16 * (i + 0)];
        float4 a1 = xr[kq + 16 * (i + 1)];
        float4 a2 = xr[kq + 16 * (i + 2)];
        float4 a3 = xr[kq + 16 * (i + 3)];
        s0 += a0.x*wv[i+0].x + a0.y*wv[i+0].y + a0.z*wv[i+0].z + a0.w*wv[i+0].w;
        s1 += a1.x*wv[i+1].x + a1.y*wv[i+1].y + a1.z*wv[i+1].z + a1.w*wv[i+1].w;
        s2 += a2.x*wv[i+2].x + a2.y*wv[i+2].y + a2.z*wv[i+2].z + a2.w*wv[i+2].w;
        s3 += a3.x*wv[i+3].x + a3.y*wv[i+3].y + a3.z*wv[i+3].z + a3.w*wv[i+3].w;
      }
      acc[r] = (s0 + s1) + (s2 + s3);
    }

    // phase 2: ONE batched butterfly over kq bits (8 independent chains)
#pragma unroll
    for (int m = 4; m <= 32; m <<= 1)
#pragma unroll
      for (int r = 0; r < RPB; ++r) acc[r] += __shfl_xor(acc[r], m, 64);

    // bias, store, batched sumsq
    float v2[RPB];
#pragma unroll
    for (int r = 0; r < RPB; ++r) {
      const float val = acc[r] + bias;
      if (kq == 0) xall[(size_t)(row0 + r) * 80 + j0 + jsub] = val;
      v2[r] = val * val;
    }
#pragma unroll
    for (int r = 0; r < RPB; ++r) v2[r] += __shfl_xor(v2[r], 1, 64);
#pragma unroll
    for (int r = 0; r < RPB; ++r) v2[r] += __shfl_xor(v2[r], 2, 64);
    if (lane == 0) {
#pragma unroll
      for (int r = 0; r < RPB; ++r) s_ss[r][w] = v2[r];
    }
    __syncthreads();
    if (tid < RPB * 2) {
      const int r = tid >> 1, s = tid & 1;   // s=0: waves 0,1  s=1: waves 2,3
      ssq[(size_t)(row0 + r) * 10 + cb * 2 + s] = s_ss[r][2 * s] + s_ss[r][2 * s + 1];
    }
  } else if (bid < PROJ_BLOCKS + N_CTRY) {
    // ---------------- country-table projection path ----------------
    float* pchat = ws + OFF_PCHAT;
    const int b = bid - PROJ_BLOCKS;
    float4 xa[3];
#pragma unroll
    for (int i = 0; i < 3; ++i)
      xa[i] = ((const float4*)(ctab + (size_t)b * BERT))[lane + 64 * i];
    float acc6[6];
#pragma unroll
    for (int jj = 0; jj < 6; ++jj) acc6[jj] = 0.f;
#pragma unroll
    for (int jj = 0; jj < 6; ++jj) {
      const int j = w * 6 + jj;
      const float4* wr = (const float4*)(W_cet + (size_t)j * BERT);
#pragma unroll
      for (int i = 0; i < 3; ++i) {
        float4 wvv = wr[lane + 64 * i];
        acc6[jj] += xa[i].x * wvv.x + xa[i].y * wvv.y + xa[i].z * wvv.z + xa[i].w * wvv.w;
      }
    }
#pragma unroll
    for (int s = 32; s >= 1; s >>= 1)
#pragma unroll
      for (int jj = 0; jj < 6; ++jj) acc6[jj] += __shfl_xor(acc6[jj], s, 64);
    if (lane == 0) {
#pragma unroll
      for (int jj = 0; jj < 6; ++jj) s_p24[w * 6 + jj] = acc6[jj] + b_cet[w * 6 + jj];
    }
    __syncthreads();
    if (tid == 0) {
      float ss = 0.f;
      for (int k = 0; k < 24; ++k) ss += s_p24[k] * s_p24[k];
      s_inv1 = 1.f / fmaxf(sqrtf(ss), 1e-8f);
    }
    __syncthreads();
    if (tid < 24) pchat[b * 24 + tid] = s_p24[tid] * s_inv1;
  } else {
    // ---------------- code-embedding normalization path ----------------
    float* codehat = ws + OFF_CODEHAT;
    const int idx = (bid - PROJ_BLOCKS - N_CTRY) * 256 + tid;
    if (idx < N_CODES) {
      float v[8];
      float ss = 0.f;
#pragma unroll
      for (int k = 0; k < 8; ++k) { v[k] = code_emb[idx * 8 + k]; ss += v[k] * v[k]; }
      const float inv = 1.f / fmaxf(sqrtf(ss), 1e-8f);
#pragma unroll
      for (int k = 0; k < 8; ++k) codehat[idx * 8 + k] = v[k] * inv;
    }
  }
}

// ---------------------------------------------------------------------------
// Kernel 2: classify, LDS-FREE (R9 post-mortem: staging pchat per block cost
// 12.3 MB L2 traffic + 24 staging rounds + 2 barriers; the 24 KB table is
// L1/L2-resident so direct float4 gathers are cheaper and LDS-free ->
// occupancy not LDS-limited). 256 threads = 4 waves = 4 rows; lane = class;
// xv/ssq wave-uniform scalar loads; softmax = one wave butterfly.
// pchat rows are 96 B (= 6 x 16 B) so cidx*24 is float4-aligned.
// ---------------------------------------------------------------------------
__global__ __launch_bounds__(256) void k_classify(
    const int* __restrict__ fcodes, const int* __restrict__ ccodes,
    const float* __restrict__ gaz,
    const float* __restrict__ W_mix1, const float* __restrict__ b_mix1,
    const float* __restrict__ W_mix2, const float* __restrict__ b_mix2,
    const float* __restrict__ W_last, const float* __restrict__ b_last,
    const float* __restrict__ ws, float* __restrict__ out) {
  const int tid = threadIdx.x;
  const int w = tid >> 6, lane = tid & 63;
  const int row0 = blockIdx.x * 4;

  const int row = __builtin_amdgcn_readfirstlane(row0 + w);
  const float* xv = ws + OFF_XALL + (size_t)row * 80;   // uniform -> s_load
  const float* q  = ws + OFF_SSQ + (size_t)row * 10;    // uniform -> s_load
  const float g0 = q[0] + q[1] + q[2];
  const float g1 = q[3];
  const float g2 = q[4] + q[5] + q[6];
  const float g3 = q[7] + q[8] + q[9];
  const float inv0 = 1.f / fmaxf(sqrtf(g0), 1e-8f);
  const float inv1 = 1.f / fmaxf(sqrtf(g1), 1e-8f);
  const float inv2 = 1.f / fmaxf(sqrtf(g2), 1e-8f);
  const float inv3 = 1.f / fmaxf(sqrtf(g3), 1e-8f);

  const int cidx = ccodes[row * CC + lane];
  const int fidx = fcodes[row * CC + lane];

  float cc[24];
  {
    const float4* p4 = (const float4*)(ws + OFF_PCHAT + cidx * 24);
#pragma unroll
    for (int i = 0; i < 6; ++i) {
      float4 v = p4[i];
      cc[4*i+0] = v.x; cc[4*i+1] = v.y; cc[4*i+2] = v.z; cc[4*i+3] = v.w;
    }
  }
  float cd[8];
  {
    const float4* q4 = (const float4*)(ws + OFF_CODEHAT + fidx * 8);
#pragma unroll
    for (int i = 0; i < 2; ++i) {
      float4 v = q4[i];
      cd[4*i+0] = v.x; cd[4*i+1] = v.y; cd[4*i+2] = v.z; cd[4*i+3] = v.w;
    }
  }

  float sc = 0.f, so = 0.f, sd = 0.f, sq = 0.f;
#pragma unroll
  for (int k = 0; k < 24; ++k) {
    const float ck = cc[k];
    sc += xv[k] * ck;
    so += xv[32 + k] * ck;
    sd += xv[56 + k] * ck;
  }
#pragma unroll
  for (int k = 0; k < 8; ++k) sq += xv[24 + k] * cd[k];

  float f[13];
  f[0] = sc * inv0;
  f[1] = sq * inv1;
  f[2] = so * inv2;
  f[3] = sd * inv3;
  {
    const float* g = gaz + (size_t)(row * CC + lane) * 9;
    float4 ga = ((const float4*)g)[0];
    float4 gb = ((const float4*)g)[1];
    f[4] = ga.x; f[5] = ga.y; f[6] = ga.z; f[7] = ga.w;
    f[8] = gb.x; f[9] = gb.y; f[10] = gb.z; f[11] = gb.w;
    f[12] = g[8];
  }

  float h1[24];
#pragma unroll
  for (int j = 0; j < 24; ++j) {
    float a = b_mix1[j];
#pragma unroll
    for (int i = 0; i < 13; ++i) a += W_mix1[j * 13 + i] * f[i];
    h1[j] = 1.f / (1.f + __expf(-a));
  }
  float h2[24];
#pragma unroll
  for (int j = 0; j < 24; ++j) {
    float a = b_mix2[j];
#pragma unroll
    for (int i = 0; i < 24; ++i) a += W_mix2[j * 24 + i] * h1[i];
    h2[j] = 1.f / (1.f + __expf(-a));
  }
  float last = b_last[0];
#pragma unroll
  for (int k = 0; k < 24; ++k) last += W_last[k] * h2[k];

  float mx = last;
#pragma unroll
  for (int s = 32; s >= 1; s >>= 1) mx = fmaxf(mx, __shfl_xor(mx, s, 64));
  const float e = __expf(last - mx);
  float ssum = e;
#pragma unroll
  for (int s = 32; s >= 1; s >>= 1) ssum += __shfl_xor(ssum, s, 64);
  out[row * CC + lane] = e / ssum;
}

// ---------------------------------------------------------------------------
extern "C" void kernel_launch(void* const* d_in, const int* in_sizes, int n_in,
                              void* d_out, int out_size, void* d_ws, size_t ws_size,
                              hipStream_t stream) {
  const float* place   = (const float*)d_in[0];
  const float* other   = (const float*)d_in[1];
  const float* doc     = (const float*)d_in[2];
  const int*   fcodes  = (const int*)d_in[3];
  const int*   ccodes  = (const int*)d_in[4];
  const float* gaz     = (const float*)d_in[5];
  const float* code_emb= (const float*)d_in[6];
  const float* ctab    = (const float*)d_in[7];
  const float* W_cet   = (const float*)d_in[8];
  const float* b_cet   = (const float*)d_in[9];
  const float* W_t2c   = (const float*)d_in[10];
  const float* b_t2c   = (const float*)d_in[11];
  const float* W_ctx   = (const float*)d_in[12];
  const float* b_ctx   = (const float*)d_in[13];
  const float* W_code  = (const float*)d_in[14];
  const float* b_code  = (const float*)d_in[15];
  const float* W_mix1  = (const float*)d_in[16];
  const float* b_mix1  = (const float*)d_in[17];
  const float* W_mix2  = (const float*)d_in[18];
  const float* b_mix2  = (const float*)d_in[19];
  const float* W_last  = (const float*)d_in[20];
  const float* b_last  = (const float*)d_in[21];
  float* ws  = (float*)d_ws;
  float* out = (float*)d_out;

  // proj (1280) + country (250) + code-norm (3) in one grid
  k_proj<<<PROJ_BLOCKS + N_CTRY + 3, 256, 0, stream>>>(
      place, other, doc, W_t2c, b_t2c, W_code, b_code, W_ctx, b_ctx,
      ctab, W_cet, b_cet, code_emb, ws);
  // classify: 4 rows/block, LDS-free
  k_classify<<<BB / 4, 256, 0, stream>>>(fcodes, ccodes, gaz, W_mix1, b_mix1,
                                         W_mix2, b_mix2, W_last, b_last, ws, out);
}